// Round 8
// baseline (10.196 us; speedup 1.0000x reference)
//
#include <hip/hip_runtime.h>
#include <math.h>

#define BB 32
#define TT 200
#define NCC 10
#define FF 2048
#define KK 3
#define NW (2 * NCC * BB * 4)   // 2560 single-wave writer blocks: (side,nc,b,fq)

typedef unsigned long long u64;

#define SENT(w)  (0x9E3779B9u * (unsigned)((w) + 1))
#define SENTB(i) (0x85EBCA6Bu * (unsigned)((i) + 7))

__device__ inline u64 pack_slot(unsigned tag, float v) {
    return ((u64)tag << 32) | (u64)__float_as_uint(v);
}

// Butterfly argmax across a 64-lane wave: max value, ties -> lower index.
// Matches jax.lax.top_k (descending, stable) — verified passing R1..R7.
__device__ inline void wave_argmax(float& v, int& i) {
    #pragma unroll
    for (int m = 1; m < 64; m <<= 1) {
        float ov = __shfl_xor(v, m);
        int   oi = __shfl_xor(i, m);
        if (ov > v || (ov == v && oi < i)) { v = ov; i = oi; }
    }
}

__device__ inline float wave_sum(float v) {
    #pragma unroll
    for (int m = 1; m < 64; m <<= 1) v += __shfl_xor(v, m);
    return v;
}

// ---------------------------------------------------------------------------
// Single node. Blocks 0..2559: single-wave writers, no LDS, no barriers.
// w = ((side*NCC+nc)*BB + b)*4 + fq. Top-3 in registers (R5 body), gather 3
// quarter-rows (2 coalesced float4 each), wave_sum, publish packed
// {sentinel|float} with a RELAXED agent atomic (no cache maintenance).
// Block 2560: composer — bulk-issues all 41 slot loads (pipelined), verifies
// tags (rare respin), composes both scalars in-register, writes d_out.
// ---------------------------------------------------------------------------
__global__ __launch_bounds__(64) void mono_kernel(
        const float* __restrict__ abnr_magn,
        const float* __restrict__ norm_magn,
        const float* __restrict__ abnr_feats,
        const float* __restrict__ norm_feats,
        const float* __restrict__ abnr_sls,
        const float* __restrict__ norm_sls,
        const float* __restrict__ abnr_u,
        const float* __restrict__ norm_u,
        u64* __restrict__ slot  /* [NW]   */,
        u64* __restrict__ bslot /* [2*BB] */,
        float* __restrict__ out) {
    const int bid  = blockIdx.x;
    const int lane = threadIdx.x;

    if (bid < NW) {
        // ---------------- writer (one wave) ----------------
        const int w    = bid;
        const int fq   = w & 3;
        const int r    = w >> 2;           // (side*NCC + nc)*BB + b
        const int b    = r % BB;
        const int sn   = r / BB;
        const int side = sn / NCC;
        const int nc   = sn % NCC;

        const float* feats = side ? norm_feats : abnr_feats;
        const float* magn  = side ? norm_magn  : abnr_magn;
        const float* u     = side ? norm_u     : abnr_u;

        // ---- masked top-3 fully in registers ----
        const float scale = 1.0f / (1.0f - 0.7f);
        float vv[4];
        int   tv[4];
        if (lane < TT / 4) {
            float4 mg = *(const float4*)(magn + b * TT + lane * 4);
            float4 uu = *(const float4*)(u    + b * TT + lane * 4);
            vv[0] = mg.x * ((uu.x >= 0.7f) ? scale : 0.0f);
            vv[1] = mg.y * ((uu.y >= 0.7f) ? scale : 0.0f);
            vv[2] = mg.z * ((uu.z >= 0.7f) ? scale : 0.0f);
            vv[3] = mg.w * ((uu.w >= 0.7f) ? scale : 0.0f);
            #pragma unroll
            for (int j = 0; j < 4; ++j) tv[j] = lane * 4 + j;
        } else {
            #pragma unroll
            for (int j = 0; j < 4; ++j) { vv[j] = -INFINITY; tv[j] = 1 << 30; }
        }
        int id[KK];
        #pragma unroll
        for (int k = 0; k < KK; ++k) {
            float bv = -INFINITY;
            int   bi = 1 << 30;
            #pragma unroll
            for (int j = 0; j < 4; ++j)
                if (vv[j] > bv || (vv[j] == bv && tv[j] < bi)) { bv = vv[j]; bi = tv[j]; }
            wave_argmax(bv, bi);
            id[k] = bi;
            #pragma unroll
            for (int j = 0; j < 4; ++j)
                if (tv[j] == bi) vv[j] = -INFINITY;
        }

        // ---- BCE term, once per (side, b) ----
        if (nc == 0 && fq == 0 && lane == 0) {
            const float* sls = side ? norm_sls : abnr_sls;
            float v = (sls[b * TT + id[0]] + sls[b * TT + id[1]] +
                       sls[b * TT + id[2]]) * (1.0f / 3.0f);
            float term = side ? fmaxf(logf(1.0f - v), -100.0f)
                              : fmaxf(logf(v), -100.0f);
            __hip_atomic_store(&bslot[side * BB + b],
                               pack_slot(SENTB(side * BB + b), term),
                               __ATOMIC_RELAXED, __HIP_MEMORY_SCOPE_AGENT);
        }

        // ---- gather: 3 rows x this F-quarter (512 floats), 2 float4/row ----
        const size_t base = (size_t)(nc * BB + b) * (TT * FF) +
                            (size_t)fq * (FF / 4) + lane * 4;
        const float* p0 = feats + base + (size_t)id[0] * FF;
        const float* p1 = feats + base + (size_t)id[1] * FF;
        const float* p2 = feats + base + (size_t)id[2] * FF;
        float4 a0 = *(const float4*)(p0);
        float4 a1 = *(const float4*)(p1);
        float4 a2 = *(const float4*)(p2);
        float4 b0 = *(const float4*)(p0 + 256);
        float4 b1 = *(const float4*)(p1 + 256);
        float4 b2 = *(const float4*)(p2 + 256);

        float m, acc = 0.0f;
        m = a0.x + a1.x + a2.x; acc += m * m;
        m = a0.y + a1.y + a2.y; acc += m * m;
        m = a0.z + a1.z + a2.z; acc += m * m;
        m = a0.w + a1.w + a2.w; acc += m * m;
        m = b0.x + b1.x + b2.x; acc += m * m;
        m = b0.y + b1.y + b2.y; acc += m * m;
        m = b0.z + b1.z + b2.z; acc += m * m;
        m = b0.w + b1.w + b2.w; acc += m * m;

        acc = wave_sum(acc);
        if (lane == 0)
            __hip_atomic_store(&slot[w], pack_slot(SENT(w), acc),
                               __ATOMIC_RELAXED, __HIP_MEMORY_SCOPE_AGENT);
        return;
    }

    // ---------------- composer (block NW, one wave) ----------------
    // Lane handles rows i = lane + 64k, k in [0,5): abnr slots 4i+j,
    // norm slots 4*(320+i)+j. Bulk-issue all loads (independent -> pipelined).
    u64 pa_u[5][4], pn_u[5][4];
    #pragma unroll
    for (int k = 0; k < 5; ++k) {
        const int i = lane + 64 * k;
        #pragma unroll
        for (int j = 0; j < 4; ++j) {
            pa_u[k][j] = __hip_atomic_load(&slot[4 * i + j], __ATOMIC_RELAXED,
                                           __HIP_MEMORY_SCOPE_AGENT);
            pn_u[k][j] = __hip_atomic_load(&slot[4 * (NCC * BB + i) + j],
                                           __ATOMIC_RELAXED, __HIP_MEMORY_SCOPE_AGENT);
        }
    }
    u64 bv = __hip_atomic_load(&bslot[lane], __ATOMIC_RELAXED,
                               __HIP_MEMORY_SCOPE_AGENT);

    // Verify tags; respin only stragglers (rare — writers usually done).
    #pragma unroll
    for (int k = 0; k < 5; ++k) {
        const int i = lane + 64 * k;
        #pragma unroll
        for (int j = 0; j < 4; ++j) {
            const unsigned ta = SENT(4 * i + j);
            while ((unsigned)(pa_u[k][j] >> 32) != ta) {
                __builtin_amdgcn_s_sleep(1);
                pa_u[k][j] = __hip_atomic_load(&slot[4 * i + j], __ATOMIC_RELAXED,
                                               __HIP_MEMORY_SCOPE_AGENT);
            }
            const unsigned tn = SENT(4 * (NCC * BB + i) + j);
            while ((unsigned)(pn_u[k][j] >> 32) != tn) {
                __builtin_amdgcn_s_sleep(1);
                pn_u[k][j] = __hip_atomic_load(&slot[4 * (NCC * BB + i) + j],
                                               __ATOMIC_RELAXED, __HIP_MEMORY_SCOPE_AGENT);
            }
        }
    }
    {
        const unsigned tb = SENTB(lane);
        while ((unsigned)(bv >> 32) != tb) {
            __builtin_amdgcn_s_sleep(1);
            bv = __hip_atomic_load(&bslot[lane], __ATOMIC_RELAXED,
                                   __HIP_MEMORY_SCOPE_AGENT);
        }
    }

    // Compose (fixed-order, deterministic).
    const float third = 1.0f / 3.0f;
    float s = 0.0f;
    #pragma unroll
    for (int k = 0; k < 5; ++k) {
        float pa = (__uint_as_float((unsigned)pa_u[k][0]) +
                    __uint_as_float((unsigned)pa_u[k][1])) +
                   (__uint_as_float((unsigned)pa_u[k][2]) +
                    __uint_as_float((unsigned)pa_u[k][3]));
        float pn = (__uint_as_float((unsigned)pn_u[k][0]) +
                    __uint_as_float((unsigned)pn_u[k][1])) +
                   (__uint_as_float((unsigned)pn_u[k][2]) +
                    __uint_as_float((unsigned)pn_u[k][3]));
        float l2a = sqrtf(pa) * third;   // ||mean over K|| = sqrt(sum((Σrows)^2))/3
        float l2n = sqrtf(pn) * third;
        float t = fabsf(100.0f - l2a) + l2n;
        s += t * t;
    }
    s = wave_sum(s);

    float s2 = __uint_as_float((unsigned)bv);   // 64 BCE terms, one per lane
    s2 = wave_sum(s2);

    if (lane == 0) {
        out[0] = 1e-4f * (s * (1.0f / (float)(NCC * BB)));
        out[1] = -s2 * (1.0f / (float)BB);
    }
}

extern "C" void kernel_launch(void* const* d_in, const int* in_sizes, int n_in,
                              void* d_out, int out_size, void* d_ws, size_t ws_size,
                              hipStream_t stream) {
    const float* abnr_magn  = (const float*)d_in[0];
    const float* norm_magn  = (const float*)d_in[1];
    const float* abnr_feats = (const float*)d_in[2];
    const float* norm_feats = (const float*)d_in[3];
    const float* abnr_sls   = (const float*)d_in[4];
    const float* norm_sls   = (const float*)d_in[5];
    const float* abnr_u     = (const float*)d_in[6];
    const float* norm_u     = (const float*)d_in[7];
    float* out = (float*)d_out;

    u64* slot  = (u64*)d_ws;                         // 2560 x 8 B
    u64* bslot = (u64*)((char*)d_ws + 32768);        // 64 x 8 B

    mono_kernel<<<NW + 1, 64, 0, stream>>>(abnr_magn, norm_magn,
                                           abnr_feats, norm_feats,
                                           abnr_sls, norm_sls,
                                           abnr_u, norm_u,
                                           slot, bslot, out);
}